// Round 6
// baseline (4669.579 us; speedup 1.0000x reference)
//
#include <hip/hip_runtime.h>
#include <cstdint>
#include <cstddef>

#define BN 64
#define TN 512
#define DN 256
#define UN 256
#define NC 768            // 3*UN, order: r | z | h
#define SLOTS (TN + 5)    // slots TN..TN+3 = initial states, TN+4 = zero slot
#define ZSLOT (TN + 4)
#define WL 6              // Ur/Uz rows per 32-row slice resident in LDS (96 KB)

__device__ __forceinline__ float sigm(float x) {
  return 1.0f / (1.0f + __expf(-x));
}
__device__ __forceinline__ float tanh_fast(float x) {
  float e = __expf(-2.0f * x);
  return 2.0f / (1.0f + e) - 1.0f;
}

// ---------------- kernel 0: concat weights + biases ----------------
__global__ __launch_bounds__(256) void build_wcat(
    const float* __restrict__ Wr, const float* __restrict__ Wz, const float* __restrict__ Wh,
    const float* __restrict__ br, const float* __restrict__ bz, const float* __restrict__ bh,
    float* __restrict__ wcat, float* __restrict__ bias)
{
  int idx = blockIdx.x * 256 + threadIdx.x;
  if (idx < DN * NC) {
    int k = idx / NC, c = idx % NC;
    float v;
    if (c < 256)      v = Wr[k * UN + c];
    else if (c < 512) v = Wz[k * UN + (c - 256)];
    else              v = Wh[k * UN + (c - 512)];
    wcat[idx] = v;
  }
  if (idx < NC) {
    bias[idx] = (idx < 256) ? br[idx] : ((idx < 512) ? bz[idx - 256] : bh[idx - 512]);
  }
}

// ---------------- kernel 1: P = X @ Wcat + bias  (fp32, LDS-tiled) ----------------
__global__ __launch_bounds__(256) void gemm_xw(
    const float* __restrict__ X, const float* __restrict__ Wc,
    const float* __restrict__ bias, float* __restrict__ P)
{
  __shared__ float As[32][68];
  __shared__ float Bs[32][64];
  const int tid = threadIdx.x;
  const int m0 = blockIdx.x * 64;
  const int n0 = blockIdx.y * 64;
  const int ty = tid >> 4, tx = tid & 15;
  float acc[4][4] = {};

  const int ar = tid >> 3;
  const int ak = (tid & 7) * 4;
  const int bk = tid >> 4;
  const int bn = (tid & 15) * 4;

  for (int k0 = 0; k0 < DN; k0 += 32) {
    float4 a0 = *(const float4*)(X + (size_t)(m0 + ar) * DN + k0 + ak);
    float4 a1 = *(const float4*)(X + (size_t)(m0 + 32 + ar) * DN + k0 + ak);
    As[ak + 0][ar] = a0.x; As[ak + 1][ar] = a0.y; As[ak + 2][ar] = a0.z; As[ak + 3][ar] = a0.w;
    As[ak + 0][32 + ar] = a1.x; As[ak + 1][32 + ar] = a1.y; As[ak + 2][32 + ar] = a1.z; As[ak + 3][32 + ar] = a1.w;
    *(float4*)&Bs[bk][bn]      = *(const float4*)(Wc + (size_t)(k0 + bk) * NC + n0 + bn);
    *(float4*)&Bs[bk + 16][bn] = *(const float4*)(Wc + (size_t)(k0 + bk + 16) * NC + n0 + bn);
    __syncthreads();
#pragma unroll
    for (int kk = 0; kk < 32; kk++) {
      float4 av = *(const float4*)&As[kk][ty * 4];
      float4 bv = *(const float4*)&Bs[kk][tx * 4];
      acc[0][0] += av.x * bv.x; acc[0][1] += av.x * bv.y; acc[0][2] += av.x * bv.z; acc[0][3] += av.x * bv.w;
      acc[1][0] += av.y * bv.x; acc[1][1] += av.y * bv.y; acc[1][2] += av.y * bv.z; acc[1][3] += av.y * bv.w;
      acc[2][0] += av.z * bv.x; acc[2][1] += av.z * bv.y; acc[2][2] += av.z * bv.z; acc[2][3] += av.z * bv.w;
      acc[3][0] += av.w * bv.x; acc[3][1] += av.w * bv.y; acc[3][2] += av.w * bv.z; acc[3][3] += av.w * bv.w;
    }
    __syncthreads();
  }
  float4 bb = *(const float4*)(bias + n0 + tx * 4);
#pragma unroll
  for (int i = 0; i < 4; i++) {
    float4 o;
    o.x = acc[i][0] + bb.x; o.y = acc[i][1] + bb.y;
    o.z = acc[i][2] + bb.z; o.w = acc[i][3] + bb.w;
    *(float4*)(P + (size_t)(m0 + ty * 4 + i) * NC + n0 + tx * 4) = o;
  }
}

// ---------------- kernel 2: the recurrence, one block per batch ----------------
// 1024 threads = 16 waves. 4 barriers per active step:
//   [A+gates fused: tid<256 gathers + computes rs/hs/zv]  bar
//   [B: Uh matvec, reg-resident wh[64], R0 recipe]         bar
//   [C redundant per wave (h via shfl broadcast) + D: 6 LDS rows + 26 streamed rows] bar
//   [E: reduce+commit (tid<512) | lx prefetch for next active step (tid>=512)]      bar
__global__ __launch_bounds__(1024, 4) void recurrent_kernel(
    const float* __restrict__ P,
    const float* __restrict__ Ur, const float* __restrict__ Uz, const float* __restrict__ Uh,
    const int* __restrict__ dep, const int* __restrict__ mask,
    const float* __restrict__ init,
    float* __restrict__ out,
    float* __restrict__ buf_s, float* __restrict__ buf_pr, float* __restrict__ buf_pz)
{
  const int b = blockIdx.x;
  const int tid = threadIdx.x;
  const int g4 = tid >> 8;        // 0..3 : B-phase k-group
  const int u  = tid & 255;
  const int wv = tid >> 6;        // 0..15
  const int mat = wv & 1;         // 0 = Ur, 1 = Uz
  const int s   = wv >> 1;        // 0..7 : 32-row slice
  const int l   = tid & 63;

  // --- Uh register-resident: column u, k in [64*g4, 64*g4+64) --- (identical to R0 recipe)
  float wh[64];
  {
    const float* pu = Uh + (size_t)(64 * g4) * UN + u;
#pragma unroll
    for (int kk = 0; kk < 64; kk++) wh[kk] = pu[(size_t)kk * UN];
  }
  const float* Um = mat ? Uz : Ur;

  __shared__ float4 wlds[2][8][WL][64];    // 96 KB LDS-resident Ur/Uz rows
  __shared__ float lxf[NC];
  __shared__ float rs[256], hs[256], zv[256];
  __shared__ float red0[4][256];
  __shared__ float redd[2][8][256];
  __shared__ float scur[256], prcur[256], pzcur[256];
  __shared__ int eff[TN], nxt[TN + 1], mloc[TN];
  __shared__ int deploc[TN * 3];

  // stage LDS-resident weight rows: rows 32s..32s+WL-1 of each slice, both matrices
  for (int i = tid; i < 2 * 8 * WL * 64; i += 1024) {
    int mm = i / (8 * WL * 64);
    int r2 = i % (8 * WL * 64);
    int ss = r2 / (WL * 64);
    int rr = (r2 / 64) % WL;
    int ll = i & 63;
    wlds[mm][ss][rr][ll] = ((const float4*)(mm ? Uz : Ur))[(size_t)(32 * ss + rr) * 64 + ll];
  }
  for (int i = tid; i < TN; i += 1024) mloc[i] = mask[b * TN + i];
  for (int i = tid; i < TN * 3; i += 1024) deploc[i] = dep[i];

  const size_t bufBase = (size_t)b * SLOTS * UN;

  if (tid < 256) {
    scur[u] = 0.0f; prcur[u] = 0.0f; pzcur[u] = 0.0f;
    buf_s[bufBase + (size_t)ZSLOT * UN + u] = 0.0f;
    buf_pr[bufBase + (size_t)ZSLOT * UN + u] = 0.0f;
    buf_pz[bufBase + (size_t)ZSLOT * UN + u] = 0.0f;
  }
  __syncthreads();

  // eff[] (last active <= t, else ZSLOT); nxt[] (next active >= t, else TN)
  if (tid == 0) {
    int e = ZSLOT;
    for (int t2 = 0; t2 < TN; t2++) { if (mloc[t2]) e = t2; eff[t2] = e; }
  } else if (tid == 64) {
    nxt[TN] = TN;
    int e = TN;
    for (int t2 = TN - 1; t2 >= 0; t2--) { if (mloc[t2]) e = t2; nxt[t2] = e; }
  }

  // prologue: initial-state projections through Ur|Uz (exact fp32; h-vector staged in rs[])
#pragma unroll 1
  for (int gg = 0; gg < 4; gg++) {
    if (tid < 256) {
      float v = init[((size_t)gg * BN + b) * UN + u];
      rs[u] = v;
      buf_s[bufBase + (size_t)(TN + gg) * UN + u] = v;
    }
    __syncthreads();
    {
      float4 a = {0, 0, 0, 0};
#pragma unroll
      for (int r = 0; r < WL; r++) {
        float hk = rs[32 * s + r];
        float4 w = wlds[mat][s][r][l];
        a.x = fmaf(hk, w.x, a.x); a.y = fmaf(hk, w.y, a.y);
        a.z = fmaf(hk, w.z, a.z); a.w = fmaf(hk, w.w, a.w);
      }
      const float4* p = (const float4*)Um + (size_t)(32 * s + WL) * 64 + l;
#pragma unroll
      for (int r = 0; r < 32 - WL; r++) {
        float hk = rs[32 * s + WL + r];
        float4 w = p[(size_t)r * 64];
        a.x = fmaf(hk, w.x, a.x); a.y = fmaf(hk, w.y, a.y);
        a.z = fmaf(hk, w.z, a.z); a.w = fmaf(hk, w.w, a.w);
      }
      *(float4*)&redd[mat][s][4 * l] = a;
    }
    __syncthreads();
    if (tid < 512) {
      int mm = tid >> 8, c = tid & 255;
      float v = 0.0f;
#pragma unroll
      for (int q = 0; q < 8; q++) v += redd[mm][q][c];
      (mm ? buf_pz : buf_pr)[bufBase + (size_t)(TN + gg) * UN + c] = v;
    }
    __syncthreads();
  }

  const size_t outB = (size_t)b * TN * UN;
  const size_t pB = (size_t)b * TN * NC;

  // preload lx for the first active step
  {
    int t0 = nxt[0];
    if (t0 < TN && tid < NC) lxf[tid] = P[pB + (size_t)t0 * NC + tid];
  }
  __syncthreads();

#pragma unroll 1
  for (int t = 0; t < TN; t++) {
    if (mloc[t] == 0) {
      if (tid < 256) out[outB + (size_t)t * UN + u] = 0.0f;
      continue;                    // no barrier on masked steps
    }
    // ---- A+gates fused (tid<256): gather 12 values + compute rs/hs/zv ----
    if (tid < 256) {
      float xr = lxf[u], xz = lxf[256 + u];
      float s0, p0, q0;
      if (t == 0) {
        size_t base = bufBase + (size_t)(TN + 0) * UN + u;
        s0 = buf_s[base]; p0 = buf_pr[base]; q0 = buf_pz[base];
      } else {
        s0 = scur[u]; p0 = prcur[u]; q0 = pzcur[u];
      }
      size_t b1 = bufBase + (size_t)((t == 0) ? (TN + 1) : eff[deploc[(t - 1) * 3 + 0]]) * UN + u;
      size_t b2 = bufBase + (size_t)((t == 0) ? (TN + 2) : eff[deploc[(t - 1) * 3 + 1]]) * UN + u;
      size_t b3 = bufBase + (size_t)((t == 0) ? (TN + 3) : eff[deploc[(t - 1) * 3 + 2]]) * UN + u;
      float s1 = buf_s[b1], s2 = buf_s[b2], s3 = buf_s[b3];
      float p1 = buf_pr[b1], p2 = buf_pr[b2], p3 = buf_pr[b3];
      float q1 = buf_pz[b1], q2 = buf_pz[b2], q3 = buf_pz[b3];
      rs[u] = sigm(xr + p0) * s0 + sigm(xr + p1) * s1
            + sigm(xr + p2) * s2 + sigm(xr + p3) * s3;
      hs[u] = (s0 + s1) + (s2 + s3);
      zv[u] = sigm(xz + ((q0 + q1) + (q2 + q3)));
    }
    __syncthreads();                               // bar1: rs/hs/zv ready
    // ---- B: full-rs @ Uh (register-resident, R0 recipe) ----
    {
      float a0 = 0, a1 = 0, a2 = 0, a3 = 0;
      const float4* v4 = (const float4*)&rs[64 * g4];
#pragma unroll
      for (int kk = 0; kk < 16; kk++) {
        float4 v = v4[kk];
        a0 += v.x * wh[4 * kk];     a1 += v.y * wh[4 * kk + 1];
        a2 += v.z * wh[4 * kk + 2]; a3 += v.w * wh[4 * kk + 3];
      }
      red0[g4][u] = (a0 + a1) + (a2 + a3);
    }
    __syncthreads();                               // bar2: red0 ready
    // ---- C (redundant per wave) + D (LDS rows + stream) fused ----
    {
      int c = 32 * s + (l & 31);
      float ht = tanh_fast(lxf[512 + c] + ((red0[0][c] + red0[1][c]) + (red0[2][c] + red0[3][c])));
      float z = zv[c];
      float hval = z * hs[c] * 0.25f + (1.0f - z) * ht;
      if (mat == 0 && l < 32) {
        scur[c] = hval;
        out[outB + (size_t)t * UN + c] = hval;
        buf_s[bufBase + (size_t)t * UN + c] = hval;
      }
      float4 a = {0, 0, 0, 0};
#pragma unroll
      for (int r = 0; r < WL; r++) {
        float hk = __shfl(hval, r);                // lane r holds col 32s+r
        float4 w = wlds[mat][s][r][l];
        a.x = fmaf(hk, w.x, a.x); a.y = fmaf(hk, w.y, a.y);
        a.z = fmaf(hk, w.z, a.z); a.w = fmaf(hk, w.w, a.w);
      }
      const float4* p = (const float4*)Um + (size_t)(32 * s + WL) * 64 + l;
#pragma unroll
      for (int r = 0; r < 32 - WL; r++) {
        float hk = __shfl(hval, WL + r);
        float4 w = p[(size_t)r * 64];
        a.x = fmaf(hk, w.x, a.x); a.y = fmaf(hk, w.y, a.y);
        a.z = fmaf(hk, w.z, a.z); a.w = fmaf(hk, w.w, a.w);
      }
      *(float4*)&redd[mat][s][4 * l] = a;
    }
    __syncthreads();                               // bar3: redd + scur ready
    // ---- E: reduce+commit | lx prefetch ----
    if (tid < 512) {
      int mm = tid >> 8, c = tid & 255;
      float v = 0.0f;
#pragma unroll
      for (int q = 0; q < 8; q++) v += redd[mm][q][c];
      if (mm == 0) { prcur[c] = v; buf_pr[bufBase + (size_t)t * UN + c] = v; }
      else         { pzcur[c] = v; buf_pz[bufBase + (size_t)t * UN + c] = v; }
    } else {
      int tn = nxt[t + 1];
      if (tn < TN) {
        int i = tid - 512;
        lxf[i] = P[pB + (size_t)tn * NC + i];
        if (i < 256) lxf[512 + i] = P[pB + (size_t)tn * NC + 512 + i];
      }
    }
    __syncthreads();                               // bar4: commits + lxf ready
  }

  // epilogue: last_out, last_state
  if (tid < 256) {
    float lst = scur[u];
    out[(size_t)BN * TN * UN + (size_t)b * UN + u] = mloc[TN - 1] ? lst : 0.0f;
    out[(size_t)BN * TN * UN + (size_t)BN * UN + (size_t)b * UN + u] = lst;
  }
}

extern "C" void kernel_launch(void* const* d_in, const int* in_sizes, int n_in,
                              void* d_out, int out_size, void* d_ws, size_t ws_size,
                              hipStream_t stream) {
  const float* inputs       = (const float*)d_in[0];
  const int*   dependencies = (const int*)d_in[1];
  const int*   mask         = (const int*)d_in[2];
  const float* initial      = (const float*)d_in[3];
  const float* Wz = (const float*)d_in[4];
  const float* Wr = (const float*)d_in[5];
  const float* Wh = (const float*)d_in[6];
  const float* Uz = (const float*)d_in[7];
  const float* Ur = (const float*)d_in[8];
  const float* Uh = (const float*)d_in[9];
  const float* bz = (const float*)d_in[10];
  const float* br = (const float*)d_in[11];
  const float* bh = (const float*)d_in[12];

  float* out = (float*)d_out;
  float* ws  = (float*)d_ws;
  float* wcat    = ws;                                   // 256*768
  float* bias    = wcat + (size_t)DN * NC;               // 768
  float* precomp = bias + NC;                            // B*T*768
  float* buf_s   = precomp + (size_t)BN * TN * NC;       // B*SLOTS*256 each
  float* buf_pr  = buf_s + (size_t)BN * SLOTS * UN;
  float* buf_pz  = buf_pr + (size_t)BN * SLOTS * UN;

  build_wcat<<<(DN * NC + 255) / 256, 256, 0, stream>>>(Wr, Wz, Wh, br, bz, bh, wcat, bias);
  gemm_xw<<<dim3(BN * TN / 64, NC / 64), 256, 0, stream>>>(inputs, wcat, bias, precomp);
  recurrent_kernel<<<BN, 1024, 0, stream>>>(precomp, Ur, Uz, Uh, dependencies, mask, initial,
                                            out, buf_s, buf_pr, buf_pz);
}